// Round 7
// baseline (354.129 us; speedup 1.0000x reference)
//
#include <hip/hip_runtime.h>

// Problem constants (match reference)
#define BATCH 8192
#define TSTEPS 200
#define FEAT 16
#define HID 32
#define GATES 128   // 4*HID, Keras order: i | f | cc | o
#define DOUT 60
#define ROWS 16     // batch rows per chain (one MFMA M-tile)
#define CH 2        // independent chains per wave (ILP to fill stalls)
#define HSTRIDE 40  // LDS h row stride in halves (80 B; write banks 2-way = free)
#define LOG2E 1.44269504088896340736f

typedef __fp16 half2v __attribute__((ext_vector_type(2)));
typedef __fp16 half8v __attribute__((ext_vector_type(8)));
typedef float  float4v __attribute__((ext_vector_type(4)));

__device__ __forceinline__ half2v pkrtz(float a, float b) {
    return __builtin_amdgcn_cvt_pkrtz(a, b);
}

// sigmoid(x) with weights/bias PRE-SCALED by log2(e): 1 / (1 + exp2(-xs))
__device__ __forceinline__ float sigm2(float xs) {
    float e = __builtin_amdgcn_exp2f(-xs);
    return __builtin_amdgcn_rcpf(1.0f + e);
}

// Single-wave block, TWO independent 16-row chains interleaved (no barriers,
// no cross-wave anything). Each chain: full 8-tile gate computation
// (4 gates x 2 unit-halves, 16x16x32 f16 MFMA). While chain A sits in its
// dependency-chain latency (LDS turnaround, trans, MFMA), chain B's ~500
// issue-cycles fill the SIMD.
//  - bias lives in persistent C-fragments (zero per-step acc-init instrs)
//  - chain-1 x A-frag = shfl_xor(chain-0 packed regs, 32): quads 0,1 of each
//    chain's A-frag carry that chain's x; quads 2,3 hit zero-padded W rows.
//  - h stored interleaved (LDS half index p = 2*(u&15) + (u>>4)); U k-rows
//    pre-permuted to match, so D->A transform is pack+write / read-b128.
// Fragment layouts (gfx950, verified m89/m91/m120):
//   A[m][k]: m = lane&15, k = (lane>>4)*8 + j
//   B[k][n]: n = lane&15, k = (lane>>4)*8 + j
//   D[m][n]: n = lane&15, m = (lane>>4)*4 + r
__global__ __launch_bounds__(64, 1) void lstm_mfma(
    const float* __restrict__ x,    // [B, T, F]
    const float* __restrict__ W,    // [F, 128]
    const float* __restrict__ U,    // [H, 128]
    const float* __restrict__ bg,   // [128]
    const float* __restrict__ W1,   // [H, 60]
    const float* __restrict__ b1,   // [60]
    const float* __restrict__ W2,   // [H, 60]
    const float* __restrict__ b2,   // [60]
    float* __restrict__ out)        // [2 * B * 60] (long || lat)
{
    const int lane = threadIdx.x;   // 0..63
    const int n16  = lane & 15;
    const int g    = lane >> 4;     // k-quad (A/B) / row-quad (D)
    const int base = blockIdx.x * (ROWS * CH);

    __shared__ __align__(16) __fp16 hbuf[CH][2][ROWS * HSTRIDE];

    // ---- stationary frags (shared by both chains) ----
    // tile (gate, uh): col = gate*32 + uh*16 + n16
    // bU k-slot s holds unit u = (s>>1) | ((s&1)<<4)  (interleaved-h match)
    // bW k-slot s holds feat s (s<16), else 0
    half8v  bU[4][2], bW[4][2];
    float4v biasF[4][2];
    #pragma unroll
    for (int gate = 0; gate < 4; gate++) {
        const float sc = (gate == 2) ? 1.0f : LOG2E;
        #pragma unroll
        for (int uh = 0; uh < 2; uh++) {
            const int col = gate * 32 + uh * 16 + n16;
            half8v u8, w8;
            #pragma unroll
            for (int j = 0; j < 8; j++) {
                const int s = g * 8 + j;
                const int u = (s >> 1) | ((s & 1) << 4);
                u8[j] = (__fp16)(U[u * GATES + col] * sc);
                w8[j] = (s < FEAT) ? (__fp16)(W[s * GATES + col] * sc) : (__fp16)0.f;
            }
            bU[gate][uh] = u8;
            bW[gate][uh] = w8;
            const float bv = bg[col] * sc;
            biasF[gate][uh] = (float4v){bv, bv, bv, bv};
        }
    }

    // zero h_0 (same-wave ordering via lgkmcnt; no barrier needed)
    #pragma unroll
    for (int c = 0; c < CH; c++)
        for (int i = lane; i < ROWS * HSTRIDE; i += 64)
            hbuf[c][0][i] = (__fp16)0.f;

    float cst[CH][2][4];
    #pragma unroll
    for (int c = 0; c < CH; c++)
        #pragma unroll
        for (int uh = 0; uh < 2; uh++)
            #pragma unroll
            for (int r = 0; r < 4; r++) cst[c][uh][r] = 0.f;

    // x: lane loads ITS chain-half's row: chain (g>>1), feats (g&1)*8..+7
    const float* xrow = x
        + (size_t)(base + (g >> 1) * ROWS + n16) * TSTEPS * FEAT + (g & 1) * 8;

    float4 xa0 = *reinterpret_cast<const float4*>(xrow);
    float4 xb0 = *reinterpret_cast<const float4*>(xrow + 4);
    float4 xa1 = *reinterpret_cast<const float4*>(xrow + FEAT);
    float4 xb1 = *reinterpret_cast<const float4*>(xrow + FEAT + 4);

    for (int t = 0; t < TSTEPS; t++) {
        // pack own chain's x_t (quads 0,1: chain0 rows; quads 2,3: chain1 rows)
        union { half8v v; half2v h2[4]; int b32[4]; } ax0, ax1;
        ax0.h2[0] = pkrtz(xa0.x, xa0.y);
        ax0.h2[1] = pkrtz(xa0.z, xa0.w);
        ax0.h2[2] = pkrtz(xb0.x, xb0.y);
        ax0.h2[3] = pkrtz(xb0.z, xb0.w);
        // chain-1 view: quads 0,1 receive chain-1 data from quads 2,3
        #pragma unroll
        for (int i = 0; i < 4; i++)
            ax1.b32[i] = __shfl_xor(ax0.b32[i], 32, 64);

        // issue x_{t+2}
        float4 xa2 = make_float4(0.f, 0.f, 0.f, 0.f), xb2 = xa2;
        if (t + 2 < TSTEPS) {
            xa2 = *reinterpret_cast<const float4*>(xrow + (size_t)(t + 2) * FEAT);
            xb2 = *reinterpret_cast<const float4*>(xrow + (size_t)(t + 2) * FEAT + 4);
        }

        // h_t A-frags for both chains (b128, same-wave lgkm ordering)
        half8v ha0 = *reinterpret_cast<const half8v*>(
            &hbuf[0][t & 1][n16 * HSTRIDE + g * 8]);
        half8v ha1 = *reinterpret_cast<const half8v*>(
            &hbuf[1][t & 1][n16 * HSTRIDE + g * 8]);

        // MFMAs: bias-C x.W then h.U, both chains (16 + 16)
        float4v acc0[4][2], acc1[4][2];
        #pragma unroll
        for (int gate = 0; gate < 4; gate++)
            #pragma unroll
            for (int uh = 0; uh < 2; uh++) {
                acc0[gate][uh] = __builtin_amdgcn_mfma_f32_16x16x32_f16(
                    ax0.v, bW[gate][uh], biasF[gate][uh], 0, 0, 0);
                acc1[gate][uh] = __builtin_amdgcn_mfma_f32_16x16x32_f16(
                    ax1.v, bW[gate][uh], biasF[gate][uh], 0, 0, 0);
            }
        #pragma unroll
        for (int gate = 0; gate < 4; gate++)
            #pragma unroll
            for (int uh = 0; uh < 2; uh++) {
                acc0[gate][uh] = __builtin_amdgcn_mfma_f32_16x16x32_f16(
                    ha0, bU[gate][uh], acc0[gate][uh], 0, 0, 0);
                acc1[gate][uh] = __builtin_amdgcn_mfma_f32_16x16x32_f16(
                    ha1, bU[gate][uh], acc1[gate][uh], 0, 0, 0);
            }

        // ---- epilogues (independent chains -> scheduler interleaves the
        //      trans-heavy sigmoid chains) ----
        #pragma unroll
        for (int c = 0; c < CH; c++) {
            float4v (*acc)[2] = (c == 0) ? acc0 : acc1;
            __fp16* hw = &hbuf[c][(t + 1) & 1][0];
            #pragma unroll
            for (int r = 0; r < 4; r++) {
                float hh[2];
                #pragma unroll
                for (int uh = 0; uh < 2; uh++) {
                    float iv = sigm2(acc[0][uh][r]);
                    float fv = sigm2(acc[1][uh][r]);
                    float cc = acc[2][uh][r];
                    float ov = sigm2(acc[3][uh][r]);
                    float cn = fmaf(fv, cst[c][uh][r], iv * fmaxf(cc, 0.f));
                    cst[c][uh][r] = cn;
                    hh[uh] = ov * fmaxf(cn, 0.f);
                }
                // one b32/row: units (n16, n16+16) at half index 2*n16
                *reinterpret_cast<half2v*>(
                    &hw[(g * 4 + r) * HSTRIDE + n16 * 2]) = pkrtz(hh[0], hh[1]);
            }
        }

        xa0 = xa1; xb0 = xb1; xa1 = xa2; xb1 = xb2;
    }

    // ---- heads: h_T interleaved layout; fp32 math ----
    for (int idx = lane; idx < CH * ROWS * DOUT; idx += 64) {
        const int row = idx / DOUT;           // 0..31
        const int d   = idx - row * DOUT;
        const __fp16* hf = &hbuf[row >> 4][TSTEPS & 1][(row & 15) * HSTRIDE];
        float s1 = b1[d], s2 = b2[d];
        #pragma unroll
        for (int u = 0; u < HID; u++) {
            const int p = ((u & 15) << 1) | (u >> 4);
            float hv = (float)hf[p];
            s1 = fmaf(hv, W1[u * DOUT + d], s1);
            s2 = fmaf(hv, W2[u * DOUT + d], s2);
        }
        out[(size_t)(base + row) * DOUT + d] = s1;
        out[(size_t)BATCH * DOUT + (size_t)(base + row) * DOUT + d] = s2;
    }
}

extern "C" void kernel_launch(void* const* d_in, const int* in_sizes, int n_in,
                              void* d_out, int out_size, void* d_ws, size_t ws_size,
                              hipStream_t stream) {
    const float* x  = (const float*)d_in[0];
    const float* W  = (const float*)d_in[1];
    const float* U  = (const float*)d_in[2];
    const float* bg = (const float*)d_in[3];
    const float* W1 = (const float*)d_in[4];
    const float* b1 = (const float*)d_in[5];
    const float* W2 = (const float*)d_in[6];
    const float* b2 = (const float*)d_in[7];
    float* out = (float*)d_out;

    dim3 grid(BATCH / (ROWS * CH));   // 256 single-wave blocks, 2 chains each
    dim3 block(64);
    lstm_mfma<<<grid, block, 0, stream>>>(x, W, U, bg, W1, b1, W2, b2, out);
}

// Round 8
// 331.131 us; speedup vs baseline: 1.0695x; 1.0695x over previous
//
#include <hip/hip_runtime.h>

// Problem constants (match reference)
#define BATCH 8192
#define TSTEPS 200
#define FEAT 16
#define HID 32
#define GATES 128   // 4*HID, Keras order: i | f | cc | o
#define DOUT 60
#define ROWS 16     // batch rows per block (one MFMA M-tile)
#define WPB 8       // waves per block; wave tl owns units [4tl, 4tl+4) x all 4 gates
#define HSTRIDE 40  // LDS h row stride in halves (80 B)
#define LOG2E 1.44269504088896340736f

typedef __fp16 half2v __attribute__((ext_vector_type(2)));
typedef __fp16 half8v __attribute__((ext_vector_type(8)));
typedef float  float4v __attribute__((ext_vector_type(4)));

__device__ __forceinline__ half2v pkrtz(float a, float b) {
    return __builtin_amdgcn_cvt_pkrtz(a, b);
}

// quad_perm DPP: cross-lane within hardware lane-quads at full VALU rate
// (NO DS pipe — 12 of these per wave-step; ds_swizzle would saturate LDS).
#define QPERM(v, ctrl) \
    __builtin_bit_cast(float, __builtin_amdgcn_mov_dpp( \
        __builtin_bit_cast(int, (v)), (ctrl), 0xf, 0xf, true))

// Workgroup barrier WITHOUT vmcnt drain: LDS visibility needs only lgkmcnt.
__device__ __forceinline__ void lgkm_barrier() {
    asm volatile("s_waitcnt lgkmcnt(0)\n\ts_barrier" ::: "memory");
}

// 8-wave MFMA LSTM with PERMUTED gate columns.
// Column permutation: tile tl (= wave) covers original cols
//   col = gate*32 + tl*4 + u_local, laid out in the tile as n16 = u_local*4+gate.
// So lane-quad {4q..4q+3} of a tile holds (i,f,cc,o) of unit tl*4+q for the
// same 4 batch rows -> gate mixing is 3 quad_perm DPP movs; c stays in lane
// gate==0. 512 blocks x 8 waves = 4096 waves = 16/CU = 4/SIMD: four
// independent step-chains share each SIMD, filling the per-chain stall that
// R4-R7 showed is insensitive to in-wave restructuring.
// Per wave per step: ds_read_b128 h -> 2 MFMA (x.W bias-C, h.U) -> 4-row
// epilogue (8 trans, 12 DPP) -> 4 b16 h-writes (gate==0 lanes) -> barrier.
// Fragment layouts (gfx950, verified m89/m91/m120):
//   A[m][k]: m = lane&15, k = (lane>>4)*8 + j
//   B[k][n]: n = lane&15, k = (lane>>4)*8 + j
//   D[m][n]: n = lane&15, m = (lane>>4)*4 + r
__global__ __launch_bounds__(512, 2) void lstm_mfma(
    const float* __restrict__ x,    // [B, T, F]
    const float* __restrict__ W,    // [F, 128]
    const float* __restrict__ U,    // [H, 128]
    const float* __restrict__ bg,   // [128]
    const float* __restrict__ W1,   // [H, 60]
    const float* __restrict__ b1,   // [60]
    const float* __restrict__ W2,   // [H, 60]
    const float* __restrict__ b2,   // [60]
    float* __restrict__ out)        // [2 * B * 60] (long || lat)
{
    const int tid  = threadIdx.x;
    const int lane = tid & 63;
    const int tl   = tid >> 6;      // wave / tile index 0..7
    const int n16  = lane & 15;
    const int g    = lane >> 4;     // k-quad (A/B) / row-quad (D)
    const int b0   = blockIdx.x * ROWS;
    const int gate = n16 & 3;       // 0=i 1=f 2=cc 3=o
    const int ul   = n16 >> 2;      // unit within tile
    const int unit = tl * 4 + ul;   // h-unit 0..31
    const int col  = gate * 32 + unit;   // original fused gate column

    __shared__ __align__(16) __fp16 hbuf[2][ROWS * HSTRIDE];

    // ---- stationary frags: this wave's single 16-col tile ----
    // sigmoid gates (i,f,o) pre-scaled by log2(e); cc unscaled.
    const float sc = (gate == 2) ? 1.0f : LOG2E;
    half8v bU, bW;
    #pragma unroll
    for (int j = 0; j < 8; j++) {
        const int s = g * 8 + j;    // k-slot: unit index (U) / feature (W)
        bU[j] = (__fp16)(U[s * GATES + col] * sc);
        bW[j] = (s < FEAT) ? (__fp16)(W[s * GATES + col] * sc) : (__fp16)0.f;
    }
    const float bv = bg[col] * sc;
    const float4v biasF = {bv, bv, bv, bv};

    // zero h_0 (visible via the t=0 loop-top barrier)
    for (int i = tid; i < ROWS * HSTRIDE; i += 512) hbuf[0][i] = (__fp16)0.f;

    float cst[4] = {0.f, 0.f, 0.f, 0.f};   // valid in gate==0 lanes

    // x: lane loads row n16, feats (g&1)*8..+7 (quads 2,3 duplicate 0,1 —
    // their K-slots hit zero-padded bW)
    const float* xrow = x + (size_t)(b0 + n16) * TSTEPS * FEAT + (g & 1) * 8;

    float4 xa0 = *reinterpret_cast<const float4*>(xrow);
    float4 xb0 = *reinterpret_cast<const float4*>(xrow + 4);
    float4 xa1 = *reinterpret_cast<const float4*>(xrow + FEAT);
    float4 xb1 = *reinterpret_cast<const float4*>(xrow + FEAT + 4);

    for (int t = 0; t < TSTEPS; t++) {
        lgkm_barrier();   // h_t visible; x prefetch stays in flight

        // h_t A-frag: row n16, units g*8..+7 (b128, 2-way banks = free)
        half8v ha = *reinterpret_cast<const half8v*>(
            &hbuf[t & 1][n16 * HSTRIDE + g * 8]);

        // issue x_{t+2}
        float4 xa2 = make_float4(0.f, 0.f, 0.f, 0.f), xb2 = xa2;
        if (t + 2 < TSTEPS) {
            xa2 = *reinterpret_cast<const float4*>(xrow + (size_t)(t + 2) * FEAT);
            xb2 = *reinterpret_cast<const float4*>(xrow + (size_t)(t + 2) * FEAT + 4);
        }

        // pack x_t A-frag
        union { half8v v; half2v h2[4]; } ax;
        ax.h2[0] = pkrtz(xa0.x, xa0.y);
        ax.h2[1] = pkrtz(xa0.z, xa0.w);
        ax.h2[2] = pkrtz(xb0.x, xb0.y);
        ax.h2[3] = pkrtz(xb0.z, xb0.w);

        // two MFMAs: acc = bias + x.W ; acc += h.U
        float4v acc = __builtin_amdgcn_mfma_f32_16x16x32_f16(ax.v, bW, biasF, 0, 0, 0);
        acc = __builtin_amdgcn_mfma_f32_16x16x32_f16(ha, bU, acc, 0, 0, 0);

        // ---- epilogue: activate own gate, quad_perm-gather, c/h in gate0 ----
        __fp16* hw = &hbuf[(t + 1) & 1][0];
        #pragma unroll
        for (int r = 0; r < 4; r++) {
            float p = acc[r];
            float e = __builtin_amdgcn_exp2f(-p);
            float s = __builtin_amdgcn_rcpf(1.0f + e);
            float a = (gate == 2) ? fmaxf(p, 0.f) : s;   // relu(cc) vs sigmoid
            // gate0 lane receives: f (lane+1), relu_cc (lane+2), o (lane+3)
            float fv = QPERM(a, 0xB1);   // [1,0,3,2]
            float cc = QPERM(a, 0x4E);   // [2,3,0,1]
            float ov = QPERM(a, 0x1B);   // [3,2,1,0]
            float cn = fmaf(fv, cst[r], a * cc);
            cst[r] = cn;
            float hn = ov * fmaxf(cn, 0.f);
            if (gate == 0)
                hw[(g * 4 + r) * HSTRIDE + unit] = (__fp16)hn;
        }

        xa0 = xa1; xb0 = xb1; xa1 = xa2; xb1 = xb2;
    }

    lgkm_barrier();   // h_T complete in hbuf[TSTEPS&1]

    // ---- heads: out = h_T @ W1/W2 + b (fp32 math, h from LDS) ----
    const __fp16* hf = &hbuf[TSTEPS & 1][0];
    for (int idx = tid; idx < ROWS * DOUT; idx += 512) {
        const int row = idx / DOUT;
        const int d   = idx - row * DOUT;
        float s1 = b1[d], s2 = b2[d];
        #pragma unroll
        for (int u = 0; u < HID; u++) {
            float hv = (float)hf[row * HSTRIDE + u];
            s1 = fmaf(hv, W1[u * DOUT + d], s1);
            s2 = fmaf(hv, W2[u * DOUT + d], s2);
        }
        out[(size_t)(b0 + row) * DOUT + d] = s1;
        out[(size_t)BATCH * DOUT + (size_t)(b0 + row) * DOUT + d] = s2;
    }
}

extern "C" void kernel_launch(void* const* d_in, const int* in_sizes, int n_in,
                              void* d_out, int out_size, void* d_ws, size_t ws_size,
                              hipStream_t stream) {
    const float* x  = (const float*)d_in[0];
    const float* W  = (const float*)d_in[1];
    const float* U  = (const float*)d_in[2];
    const float* bg = (const float*)d_in[3];
    const float* W1 = (const float*)d_in[4];
    const float* b1 = (const float*)d_in[5];
    const float* W2 = (const float*)d_in[6];
    const float* b2 = (const float*)d_in[7];
    float* out = (float*)d_out;

    dim3 grid(BATCH / ROWS);   // 512 blocks x 8 waves = 4096 waves = 16/CU
    dim3 block(64 * WPB);
    lstm_mfma<<<grid, block, 0, stream>>>(x, W, U, bg, W1, b1, W2, b2, out);
}